// Round 1
// baseline (378.983 us; speedup 1.0000x reference)
//
#include <hip/hip_runtime.h>
#include <math.h>

// Problem constants
#define T_SEQ 2048
#define NH    16
#define NKV   4
#define HD    64
// ws layout (f16 buffers), total 22 MiB:
//   Qr: [b][h][t][64]   f16, RoPE'd, pre-scaled by 0.125   (8 MiB)
//   Kr: [b][kh][t][64]  f16, RoPE'd                        (2 MiB)
//   Vt: [b][kh][d][t]   f16 (transposed for PV B-frags)    (2 MiB)
//   Wt: [n][k]          f16 (w_out transposed)             (2 MiB)
//   AO: [b*t][h*64+d]   f16 attention output (GEMM A)      (8 MiB)

typedef __attribute__((ext_vector_type(8))) _Float16 f16x8;
typedef __attribute__((ext_vector_type(4))) _Float16 f16x4;
typedef __attribute__((ext_vector_type(4))) float    f32x4;

// ---------------- prep kernels ----------------

__global__ __launch_bounds__(256) void rope_q_kernel(const float* __restrict__ q,
                                                     _Float16* __restrict__ Qr)
{
    int idx = blockIdx.x * 256 + threadIdx.x;     // [0, 2*16*2048*32)
    int i   = idx & 31;
    int t   = (idx >> 5) & 2047;
    int bh  = idx >> 16;                          // b*16+h, 0..31
    float inv = expf((float)i * (-9.210340371976184f / 32.0f));  // 10000^(-i/32)
    float ang = (float)t * inv;
    float sn = sinf(ang), cs = cosf(ang);
    const float* src = q + ((size_t)(bh >> 4) * T_SEQ + t) * 1024 + (bh & 15) * 64 + i;
    float x1 = src[0], x2 = src[32];
    _Float16* dst = Qr + ((size_t)bh * T_SEQ + t) * 64 + i;
    dst[0]  = (_Float16)((x1 * cs - x2 * sn) * 0.125f);   // fold 1/sqrt(64)
    dst[32] = (_Float16)((x2 * cs + x1 * sn) * 0.125f);
}

__global__ __launch_bounds__(256) void rope_k_kernel(const float* __restrict__ k,
                                                     _Float16* __restrict__ Kr)
{
    int idx = blockIdx.x * 256 + threadIdx.x;     // [0, 2*4*2048*32)
    int i   = idx & 31;
    int t   = (idx >> 5) & 2047;
    int bk  = idx >> 16;                          // b*4+kh, 0..7
    float inv = expf((float)i * (-9.210340371976184f / 32.0f));
    float ang = (float)t * inv;
    float sn = sinf(ang), cs = cosf(ang);
    const float* src = k + ((size_t)(bk >> 2) * T_SEQ + t) * 256 + (bk & 3) * 64 + i;
    float x1 = src[0], x2 = src[32];
    _Float16* dst = Kr + ((size_t)bk * T_SEQ + t) * 64 + i;
    dst[0]  = (_Float16)(x1 * cs - x2 * sn);
    dst[32] = (_Float16)(x2 * cs + x1 * sn);
}

__global__ __launch_bounds__(256) void prep_v_kernel(const float* __restrict__ v,
                                                     _Float16* __restrict__ Vt)
{
    int idx = blockIdx.x * 256 + threadIdx.x;     // [0, 2*4*64*2048)
    int t  = idx & 2047;
    int d  = (idx >> 11) & 63;
    int bk = idx >> 17;                           // b*4+kh
    Vt[((size_t)bk * 64 + d) * T_SEQ + t] =
        (_Float16)v[((size_t)(bk >> 2) * T_SEQ + t) * 256 + (bk & 3) * 64 + d];
}

__global__ __launch_bounds__(256) void prep_w_kernel(const float* __restrict__ w,
                                                     _Float16* __restrict__ Wt)
{
    int idx = blockIdx.x * 256 + threadIdx.x;     // [0, 1024*1024)
    int kk = idx & 1023;
    int n  = idx >> 10;
    Wt[(size_t)n * 1024 + kk] = (_Float16)w[(size_t)kk * 1024 + n];
}

// ---------------- flash attention ----------------
// One wave per (b, h, 16-row q-block). Swapped QK^T: S^T = mfma(K, Q) so
// acc has col = q (lane&15), row = key_local (4*(lane>>4)+j). Each lane then
// holds P[q][key 4g+j] -- exactly the A-frag layout of mfma_f32_16x16x16f16
// for the PV step (zero cross-lane movement for P).

__global__ __launch_bounds__(256) void attn_kernel(const _Float16* __restrict__ Qr,
                                                   const _Float16* __restrict__ Kr,
                                                   const _Float16* __restrict__ Vt,
                                                   _Float16* __restrict__ AO)
{
    const int wid  = threadIdx.x >> 6;
    const int lane = threadIdx.x & 63;
    const int W  = blockIdx.x * 4 + wid;          // 0..4095
    const int qb = W & 127;                       // q-block (16 rows)
    const int bh = W >> 7;                        // b*16+h
    const int b  = bh >> 4, h = bh & 15;
    const int kh = h >> 2;                        // GQA: 4 q-heads per kv-head
    const int g = lane >> 4, r = lane & 15;

    // Q as B-operand: lane holds Q[q = qb*16 + r][d = dh*32 + 8g + j]
    const _Float16* qp = Qr + ((size_t)bh * T_SEQ + qb * 16 + r) * 64 + 8 * g;
    f16x8 qa0 = *(const f16x8*)(qp);
    f16x8 qa1 = *(const f16x8*)(qp + 32);

    f32x4 o0 = {0.f,0.f,0.f,0.f}, o1 = o0, o2 = o0, o3 = o0;  // O[q][d], 4 d-blocks
    float m = -INFINITY, ln = 0.0f;               // online-softmax state for q = r

    const _Float16* kp0 = Kr + ((size_t)(b * NKV + kh) * T_SEQ + r) * 64 + 8 * g;
    const _Float16* vp0 = Vt + ((size_t)(b * NKV + kh) * 64 + r) * T_SEQ;

    for (int kvb = 0; kvb <= qb; ++kvb) {
        const int kbase = kvb * 16;
        // K as A-operand: lane holds K[key = kbase + r][d = dh*32 + 8g + j]
        const _Float16* kp = kp0 + (size_t)kbase * 64;
        f16x8 ka0 = *(const f16x8*)(kp);
        f16x8 ka1 = *(const f16x8*)(kp + 32);
        f32x4 st = {0.f,0.f,0.f,0.f};
        st = __builtin_amdgcn_mfma_f32_16x16x32_f16(ka0, qa0, st, 0, 0, 0);
        st = __builtin_amdgcn_mfma_f32_16x16x32_f16(ka1, qa1, st, 0, 0, 0);
        float s0 = st[0], s1 = st[1], s2 = st[2], s3 = st[3];
        if (kvb == qb) {  // diagonal block: key_local = 4g+j valid iff <= r
            if (4*g + 0 > r) s0 = -1e9f;
            if (4*g + 1 > r) s1 = -1e9f;
            if (4*g + 2 > r) s2 = -1e9f;
            if (4*g + 3 > r) s3 = -1e9f;
        }
        // row (per-q) max over 16 keys: in-lane 4 + across the 4 row-groups
        float pm = fmaxf(fmaxf(s0, s1), fmaxf(s2, s3));
        pm = fmaxf(pm, __shfl_xor(pm, 16));
        pm = fmaxf(pm, __shfl_xor(pm, 32));
        float mn   = fmaxf(m, pm);
        float corr = __expf(m - mn);              // m=-inf first iter -> 0
        float p0 = __expf(s0 - mn);
        float p1 = __expf(s1 - mn);
        float p2 = __expf(s2 - mn);
        float p3 = __expf(s3 - mn);
        float ps = p0 + p1 + p2 + p3;
        ps += __shfl_xor(ps, 16);
        ps += __shfl_xor(ps, 32);
        ln = ln * corr + ps;
        m = mn;
        // O rows are q_local = 4g+j -> fetch their corr from lanes 0..15
        f32x4 cf = { __shfl(corr, 4*g + 0), __shfl(corr, 4*g + 1),
                     __shfl(corr, 4*g + 2), __shfl(corr, 4*g + 3) };
        o0 *= cf; o1 *= cf; o2 *= cf; o3 *= cf;
        // P as A-frag (k = 4g+j matches lane's p order)
        f16x4 pf = { (_Float16)p0, (_Float16)p1, (_Float16)p2, (_Float16)p3 };
        // V as B-frag: lane holds V[key = kbase + 4g+j][d = db*16 + r]
        const _Float16* vp = vp0 + kbase + 4 * g;
        f16x4 v0 = *(const f16x4*)(vp);
        f16x4 v1 = *(const f16x4*)(vp + 16 * T_SEQ);
        f16x4 v2 = *(const f16x4*)(vp + 32 * T_SEQ);
        f16x4 v3 = *(const f16x4*)(vp + 48 * T_SEQ);
        o0 = __builtin_amdgcn_mfma_f32_16x16x16f16(pf, v0, o0, 0, 0, 0);
        o1 = __builtin_amdgcn_mfma_f32_16x16x16f16(pf, v1, o1, 0, 0, 0);
        o2 = __builtin_amdgcn_mfma_f32_16x16x16f16(pf, v2, o2, 0, 0, 0);
        o3 = __builtin_amdgcn_mfma_f32_16x16x16f16(pf, v3, o3, 0, 0, 0);
    }
    f32x4 li = { 1.0f / __shfl(ln, 4*g + 0), 1.0f / __shfl(ln, 4*g + 1),
                 1.0f / __shfl(ln, 4*g + 2), 1.0f / __shfl(ln, 4*g + 3) };
    o0 *= li; o1 *= li; o2 *= li; o3 *= li;
    // D layout: row = q_local = 4g+j, col = d_local = r (per d-block)
    _Float16* ao = AO + ((size_t)b * T_SEQ + qb * 16) * 1024 + h * 64 + r;
    #pragma unroll
    for (int j = 0; j < 4; ++j) {
        ao[(size_t)(4*g + j) * 1024 +  0] = (_Float16)o0[j];
        ao[(size_t)(4*g + j) * 1024 + 16] = (_Float16)o1[j];
        ao[(size_t)(4*g + j) * 1024 + 32] = (_Float16)o2[j];
        ao[(size_t)(4*g + j) * 1024 + 48] = (_Float16)o3[j];
    }
}

// ---------------- projection GEMM: out[4096][1024] = AO * Wt^T ----------------
// 128x128 tile, BK=32, 4 waves each computing 64x64 via 4x4 16x16x32 MFMAs.

__global__ __launch_bounds__(256) void gemm_kernel(const _Float16* __restrict__ A,
                                                   const _Float16* __restrict__ Bt,
                                                   float* __restrict__ C)
{
    __shared__ _Float16 As[128 * 32];
    __shared__ _Float16 Bs[128 * 32];
    const int tid  = threadIdx.x;
    const int bx   = blockIdx.x;                  // n-tile 0..7
    const int by   = blockIdx.y;                  // m-tile 0..31
    const int lane = tid & 63;
    const int wid  = tid >> 6;
    const int g = lane >> 4, r = lane & 15;
    const int wm = wid >> 1, wn = wid & 1;

    f32x4 acc[4][4];
    #pragma unroll
    for (int i = 0; i < 4; ++i)
        #pragma unroll
        for (int j = 0; j < 4; ++j) acc[i][j] = (f32x4){0.f,0.f,0.f,0.f};

    // chunk c covers tile elements [c*8, c*8+8): row = c>>2, koff = (c&3)*8
    const int c0 = tid, c1 = tid + 256;
    const size_t a0off = (size_t)(by*128 + (c0 >> 2)) * 1024 + (c0 & 3) * 8;
    const size_t a1off = (size_t)(by*128 + (c1 >> 2)) * 1024 + (c1 & 3) * 8;
    const size_t b0off = (size_t)(bx*128 + (c0 >> 2)) * 1024 + (c0 & 3) * 8;
    const size_t b1off = (size_t)(bx*128 + (c1 >> 2)) * 1024 + (c1 & 3) * 8;

    for (int kt = 0; kt < 32; ++kt) {
        f16x8 a0 = *(const f16x8*)(A  + a0off + kt * 32);
        f16x8 a1 = *(const f16x8*)(A  + a1off + kt * 32);
        f16x8 b0 = *(const f16x8*)(Bt + b0off + kt * 32);
        f16x8 b1 = *(const f16x8*)(Bt + b1off + kt * 32);
        __syncthreads();                          // prior iter's reads done
        *(f16x8*)(&As[c0 * 8]) = a0;
        *(f16x8*)(&As[c1 * 8]) = a1;
        *(f16x8*)(&Bs[c0 * 8]) = b0;
        *(f16x8*)(&Bs[c1 * 8]) = b1;
        __syncthreads();
        f16x8 af[4], bfv[4];
        #pragma unroll
        for (int mi = 0; mi < 4; ++mi)
            af[mi] = *(const f16x8*)(&As[(wm*64 + mi*16 + r) * 32 + 8 * g]);
        #pragma unroll
        for (int ni = 0; ni < 4; ++ni)
            bfv[ni] = *(const f16x8*)(&Bs[(wn*64 + ni*16 + r) * 32 + 8 * g]);
        #pragma unroll
        for (int mi = 0; mi < 4; ++mi)
            #pragma unroll
            for (int ni = 0; ni < 4; ++ni)
                acc[mi][ni] = __builtin_amdgcn_mfma_f32_16x16x32_f16(
                                  af[mi], bfv[ni], acc[mi][ni], 0, 0, 0);
    }
    #pragma unroll
    for (int mi = 0; mi < 4; ++mi)
        #pragma unroll
        for (int ni = 0; ni < 4; ++ni)
            #pragma unroll
            for (int j = 0; j < 4; ++j)
                C[(size_t)(by*128 + wm*64 + mi*16 + 4*g + j) * 1024
                  + bx*128 + wn*64 + ni*16 + r] = acc[mi][ni][j];
}

// ---------------- launch ----------------

extern "C" void kernel_launch(void* const* d_in, const int* in_sizes, int n_in,
                              void* d_out, int out_size, void* d_ws, size_t ws_size,
                              hipStream_t stream) {
    const float* q = (const float*)d_in[0];
    const float* k = (const float*)d_in[1];
    const float* v = (const float*)d_in[2];
    const float* w = (const float*)d_in[3];
    float* out = (float*)d_out;

    char* ws = (char*)d_ws;                       // needs 22 MiB
    _Float16* Qr = (_Float16*)(ws);
    _Float16* Kr = (_Float16*)(ws + ((size_t)8  << 20));
    _Float16* Vt = (_Float16*)(ws + ((size_t)10 << 20));
    _Float16* Wt = (_Float16*)(ws + ((size_t)12 << 20));
    _Float16* AO = (_Float16*)(ws + ((size_t)14 << 20));

    hipLaunchKernelGGL(rope_q_kernel, dim3(8192), dim3(256), 0, stream, q, Qr);
    hipLaunchKernelGGL(rope_k_kernel, dim3(2048), dim3(256), 0, stream, k, Kr);
    hipLaunchKernelGGL(prep_v_kernel, dim3(4096), dim3(256), 0, stream, v, Vt);
    hipLaunchKernelGGL(prep_w_kernel, dim3(4096), dim3(256), 0, stream, w, Wt);
    hipLaunchKernelGGL(attn_kernel,   dim3(1024), dim3(256), 0, stream, Qr, Kr, Vt, AO);
    hipLaunchKernelGGL(gemm_kernel,   dim3(8, 32), dim3(256), 0, stream, AO, Wt, out);
}

// Round 2
// 96.239 us; speedup vs baseline: 3.9380x; 3.9380x over previous
//
#include <hip/hip_runtime.h>
#include <math.h>

// Problem constants
#define T_SEQ 2048
#define NH    16
#define NKV   4
#define HD    64
// ws layout (f16 buffers), total 22 MiB:
//   Qr: [b][h][t][64]   f16, RoPE'd, pre-scaled by 0.125   (8 MiB)
//   Kr: [b][kh][t][64]  f16, RoPE'd                        (2 MiB)
//   Vt: [b][kh][d][t]   f16 (transposed for PV B-frags)    (2 MiB)
//   Wt: [n][k]          f16 (w_out transposed)             (2 MiB)
//   AO: [b*t][h*64+d]   f16 attention output (GEMM A)      (8 MiB)

typedef __attribute__((ext_vector_type(8))) _Float16 f16x8;
typedef __attribute__((ext_vector_type(4))) _Float16 f16x4;
typedef __attribute__((ext_vector_type(4))) float    f32x4;

// ---------------- prep kernels ----------------

__global__ __launch_bounds__(256) void rope_q_kernel(const float* __restrict__ q,
                                                     _Float16* __restrict__ Qr)
{
    int idx = blockIdx.x * 256 + threadIdx.x;     // [0, 2*16*2048*32)
    int i   = idx & 31;
    int t   = (idx >> 5) & 2047;
    int bh  = idx >> 16;                          // b*16+h, 0..31
    float inv = expf((float)i * (-9.210340371976184f / 32.0f));  // 10000^(-i/32)
    float ang = (float)t * inv;
    float sn = sinf(ang), cs = cosf(ang);
    const float* src = q + ((size_t)(bh >> 4) * T_SEQ + t) * 1024 + (bh & 15) * 64 + i;
    float x1 = src[0], x2 = src[32];
    _Float16* dst = Qr + ((size_t)bh * T_SEQ + t) * 64 + i;
    dst[0]  = (_Float16)((x1 * cs - x2 * sn) * 0.125f);   // fold 1/sqrt(64)
    dst[32] = (_Float16)((x2 * cs + x1 * sn) * 0.125f);
}

__global__ __launch_bounds__(256) void rope_k_kernel(const float* __restrict__ k,
                                                     _Float16* __restrict__ Kr)
{
    int idx = blockIdx.x * 256 + threadIdx.x;     // [0, 2*4*2048*32)
    int i   = idx & 31;
    int t   = (idx >> 5) & 2047;
    int bk  = idx >> 16;                          // b*4+kh, 0..7
    float inv = expf((float)i * (-9.210340371976184f / 32.0f));
    float ang = (float)t * inv;
    float sn = sinf(ang), cs = cosf(ang);
    const float* src = k + ((size_t)(bk >> 2) * T_SEQ + t) * 256 + (bk & 3) * 64 + i;
    float x1 = src[0], x2 = src[32];
    _Float16* dst = Kr + ((size_t)bk * T_SEQ + t) * 64 + i;
    dst[0]  = (_Float16)(x1 * cs - x2 * sn);
    dst[32] = (_Float16)(x2 * cs + x1 * sn);
}

__global__ __launch_bounds__(256) void prep_v_kernel(const float* __restrict__ v,
                                                     _Float16* __restrict__ Vt)
{
    int idx = blockIdx.x * 256 + threadIdx.x;     // [0, 2*4*64*2048)
    int t  = idx & 2047;
    int d  = (idx >> 11) & 63;
    int bk = idx >> 17;                           // b*4+kh
    Vt[((size_t)bk * 64 + d) * T_SEQ + t] =
        (_Float16)v[((size_t)(bk >> 2) * T_SEQ + t) * 256 + (bk & 3) * 64 + d];
}

__global__ __launch_bounds__(256) void prep_w_kernel(const float* __restrict__ w,
                                                     _Float16* __restrict__ Wt)
{
    int idx = blockIdx.x * 256 + threadIdx.x;     // [0, 1024*1024)
    int kk = idx & 1023;
    int n  = idx >> 10;
    Wt[(size_t)n * 1024 + kk] = (_Float16)w[(size_t)kk * 1024 + n];
}

// ---------------- flash attention (KVBLK=64, LDS-staged, double-buffered) ----
// Block = 4 waves = 64 q-rows of one (b,h). Swapped QK^T (S^T = mfma(K,Q)) so
// each lane's P values are already the A-frag layout for PV's 16x16x16 MFMA.
// K staged in LDS as [key][d], V as [d][key] (from pre-transposed Vt), both
// XOR-swizzled on 16B chunks (chunk ^= row&7) => conflict-free b128/b64 reads.

__global__ __launch_bounds__(256) void attn_kernel(const _Float16* __restrict__ Qr,
                                                   const _Float16* __restrict__ Kr,
                                                   const _Float16* __restrict__ Vt,
                                                   _Float16* __restrict__ AO)
{
    __shared__ _Float16 Ks[2][64 * 64];
    __shared__ _Float16 Vs[2][64 * 64];

    const int wid  = threadIdx.x >> 6;
    const int lane = threadIdx.x & 63;
    const int bh     = blockIdx.x & 31;           // b*16+h
    const int qblock = 31 - (blockIdx.x >> 5);    // longest blocks dispatch first
    const int b  = bh >> 4, h = bh & 15;
    const int kh = h >> 2;
    const int bkh = b * NKV + kh;
    const int g = lane >> 4, r = lane & 15;

    // Q as B-operand: lane holds Q[q = qbase + wid*16 + r][d = 8g+j (+32)]
    const _Float16* qp = Qr + ((size_t)bh * T_SEQ + qblock * 64 + wid * 16 + r) * 64 + 8 * g;
    f16x8 qa0 = *(const f16x8*)(qp);
    f16x8 qa1 = *(const f16x8*)(qp + 32);

    // staging geometry: each wave stages 16 rows of K-tile and 16 rows of V-tile
    const int srow   = wid * 16 + (lane >> 3);    // rows srow, srow+8
    const int schunk = lane & 7;                  // 16B chunk within 128B row
    const _Float16* kgbase = Kr + (size_t)bkh * T_SEQ * 64;
    const _Float16* vgbase = Vt + (size_t)bkh * 64 * T_SEQ;
    const int kd0 = srow * 64 + ((schunk ^ (srow & 7)) * 8);   // swizzled dest
    const int kd1 = kd0 + 8 * 64;                              // (srow+8)&7 == srow&7

    f16x8 stK0, stK1, stV0, stV1;
    {   // prologue: stage tile 0 into buf 0
        const _Float16* kg = kgbase + (size_t)srow * 64 + schunk * 8;
        stK0 = *(const f16x8*)(kg);
        stK1 = *(const f16x8*)(kg + 8 * 64);
        const _Float16* vg = vgbase + (size_t)srow * T_SEQ + schunk * 8;
        stV0 = *(const f16x8*)(vg);
        stV1 = *(const f16x8*)(vg + 8 * T_SEQ);
        *(f16x8*)(&Ks[0][kd0]) = stK0;
        *(f16x8*)(&Ks[0][kd1]) = stK1;
        *(f16x8*)(&Vs[0][kd0]) = stV0;
        *(f16x8*)(&Vs[0][kd1]) = stV1;
    }
    __syncthreads();

    f32x4 o0 = {0.f,0.f,0.f,0.f}, o1 = o0, o2 = o0, o3 = o0;   // O[q][4 d-blocks]
    float m = -INFINITY, ln = 0.0f;
    int cur = 0;

    for (int kvb = 0; kvb <= qblock; ++kvb) {
        // issue next tile's global loads early (latency hides under compute)
        if (kvb < qblock) {
            const int nb = (kvb + 1) * 64;
            const _Float16* kg = kgbase + (size_t)(nb + srow) * 64 + schunk * 8;
            stK0 = *(const f16x8*)(kg);
            stK1 = *(const f16x8*)(kg + 8 * 64);
            const _Float16* vg = vgbase + (size_t)srow * T_SEQ + nb + schunk * 8;
            stV0 = *(const f16x8*)(vg);
            stV1 = *(const f16x8*)(vg + 8 * T_SEQ);
        }

        const _Float16* ks = Ks[cur];
        const _Float16* vs = Vs[cur];
        const int ktmax = (kvb == qblock) ? wid : 3;   // skip fully-masked diag ktiles

        // QK^T: S^T[key][q] per 16-key ktile
        f32x4 stt[4];
        #pragma unroll
        for (int kt = 0; kt < 4; ++kt) {
            if (kt <= ktmax) {
                f16x8 ka0 = *(const f16x8*)(ks + (kt*16 + r) * 64 + ((g       ^ (r & 7)) * 8));
                f16x8 ka1 = *(const f16x8*)(ks + (kt*16 + r) * 64 + (((4 + g) ^ (r & 7)) * 8));
                f32x4 st = {0.f,0.f,0.f,0.f};
                st = __builtin_amdgcn_mfma_f32_16x16x32_f16(ka0, qa0, st, 0, 0, 0);
                st = __builtin_amdgcn_mfma_f32_16x16x32_f16(ka1, qa1, st, 0, 0, 0);
                stt[kt] = st;
            } else {
                stt[kt] = (f32x4){-1e9f, -1e9f, -1e9f, -1e9f};
            }
        }
        if (kvb == qblock) {   // diagonal: mask key > q
            #pragma unroll
            for (int kt = 0; kt < 4; ++kt)
                #pragma unroll
                for (int j = 0; j < 4; ++j)
                    if (kt*16 + 4*g + j > wid*16 + r) stt[kt][j] = -1e9f;
        }

        // online softmax over 64 keys (row = q = lane&15 column of S^T)
        float pm = -1e9f;
        #pragma unroll
        for (int kt = 0; kt < 4; ++kt)
            pm = fmaxf(pm, fmaxf(fmaxf(stt[kt][0], stt[kt][1]),
                                 fmaxf(stt[kt][2], stt[kt][3])));
        pm = fmaxf(pm, __shfl_xor(pm, 16));
        pm = fmaxf(pm, __shfl_xor(pm, 32));
        float mn   = fmaxf(m, pm);
        float corr = __expf(m - mn);
        float ps = 0.0f;
        f16x4 pf[4];
        #pragma unroll
        for (int kt = 0; kt < 4; ++kt) {
            float p0 = __expf(stt[kt][0] - mn);
            float p1 = __expf(stt[kt][1] - mn);
            float p2 = __expf(stt[kt][2] - mn);
            float p3 = __expf(stt[kt][3] - mn);
            ps += (p0 + p1) + (p2 + p3);
            pf[kt] = (f16x4){(_Float16)p0, (_Float16)p1, (_Float16)p2, (_Float16)p3};
        }
        ps += __shfl_xor(ps, 16);
        ps += __shfl_xor(ps, 32);
        ln = ln * corr + ps;
        m = mn;
        f32x4 cf = { __shfl(corr, 4*g + 0), __shfl(corr, 4*g + 1),
                     __shfl(corr, 4*g + 2), __shfl(corr, 4*g + 3) };
        o0 *= cf; o1 *= cf; o2 *= cf; o3 *= cf;

        // PV: V[key = kt*16+4g+j][d = db*16 + r] from Vs[d][key] (swizzled)
        #pragma unroll
        for (int kt = 0; kt < 4; ++kt) {
            if (kt <= ktmax) {
                const int vc = ((2*kt + (g >> 1)) ^ (r & 7)) * 8 + (g & 1) * 4;
                f16x4 v0 = *(const f16x4*)(vs + (0*16 + r) * 64 + vc);
                f16x4 v1 = *(const f16x4*)(vs + (1*16 + r) * 64 + vc);
                f16x4 v2 = *(const f16x4*)(vs + (2*16 + r) * 64 + vc);
                f16x4 v3 = *(const f16x4*)(vs + (3*16 + r) * 64 + vc);
                o0 = __builtin_amdgcn_mfma_f32_16x16x16f16(pf[kt], v0, o0, 0, 0, 0);
                o1 = __builtin_amdgcn_mfma_f32_16x16x16f16(pf[kt], v1, o1, 0, 0, 0);
                o2 = __builtin_amdgcn_mfma_f32_16x16x16f16(pf[kt], v2, o2, 0, 0, 0);
                o3 = __builtin_amdgcn_mfma_f32_16x16x16f16(pf[kt], v3, o3, 0, 0, 0);
            }
        }

        // write next tile into the other buffer (readers of it synced last iter)
        if (kvb < qblock) {
            *(f16x8*)(&Ks[cur ^ 1][kd0]) = stK0;
            *(f16x8*)(&Ks[cur ^ 1][kd1]) = stK1;
            *(f16x8*)(&Vs[cur ^ 1][kd0]) = stV0;
            *(f16x8*)(&Vs[cur ^ 1][kd1]) = stV1;
            cur ^= 1;
        }
        __syncthreads();
    }

    f32x4 li = { 1.0f / __shfl(ln, 4*g + 0), 1.0f / __shfl(ln, 4*g + 1),
                 1.0f / __shfl(ln, 4*g + 2), 1.0f / __shfl(ln, 4*g + 3) };
    o0 *= li; o1 *= li; o2 *= li; o3 *= li;
    _Float16* ao = AO + ((size_t)b * T_SEQ + qblock * 64 + wid * 16) * 1024 + h * 64 + r;
    #pragma unroll
    for (int j = 0; j < 4; ++j) {
        ao[(size_t)(4*g + j) * 1024 +  0] = (_Float16)o0[j];
        ao[(size_t)(4*g + j) * 1024 + 16] = (_Float16)o1[j];
        ao[(size_t)(4*g + j) * 1024 + 32] = (_Float16)o2[j];
        ao[(size_t)(4*g + j) * 1024 + 48] = (_Float16)o3[j];
    }
}

// ---------------- projection GEMM: out[4096][1024] = AO * Wt^T ----------------
// 128x128 tile, BK=32, 4 waves each computing 64x64 via 4x4 16x16x32 MFMAs.

__global__ __launch_bounds__(256) void gemm_kernel(const _Float16* __restrict__ A,
                                                   const _Float16* __restrict__ Bt,
                                                   float* __restrict__ C)
{
    __shared__ _Float16 As[128 * 32];
    __shared__ _Float16 Bs[128 * 32];
    const int tid  = threadIdx.x;
    const int bx   = blockIdx.x;                  // n-tile 0..7
    const int by   = blockIdx.y;                  // m-tile 0..31
    const int lane = tid & 63;
    const int wid  = tid >> 6;
    const int g = lane >> 4, r = lane & 15;
    const int wm = wid >> 1, wn = wid & 1;

    f32x4 acc[4][4];
    #pragma unroll
    for (int i = 0; i < 4; ++i)
        #pragma unroll
        for (int j = 0; j < 4; ++j) acc[i][j] = (f32x4){0.f,0.f,0.f,0.f};

    // chunk c covers tile elements [c*8, c*8+8): row = c>>2, koff = (c&3)*8
    const int c0 = tid, c1 = tid + 256;
    const size_t a0off = (size_t)(by*128 + (c0 >> 2)) * 1024 + (c0 & 3) * 8;
    const size_t a1off = (size_t)(by*128 + (c1 >> 2)) * 1024 + (c1 & 3) * 8;
    const size_t b0off = (size_t)(bx*128 + (c0 >> 2)) * 1024 + (c0 & 3) * 8;
    const size_t b1off = (size_t)(bx*128 + (c1 >> 2)) * 1024 + (c1 & 3) * 8;

    for (int kt = 0; kt < 32; ++kt) {
        f16x8 a0 = *(const f16x8*)(A  + a0off + kt * 32);
        f16x8 a1 = *(const f16x8*)(A  + a1off + kt * 32);
        f16x8 b0 = *(const f16x8*)(Bt + b0off + kt * 32);
        f16x8 b1 = *(const f16x8*)(Bt + b1off + kt * 32);
        __syncthreads();                          // prior iter's reads done
        *(f16x8*)(&As[c0 * 8]) = a0;
        *(f16x8*)(&As[c1 * 8]) = a1;
        *(f16x8*)(&Bs[c0 * 8]) = b0;
        *(f16x8*)(&Bs[c1 * 8]) = b1;
        __syncthreads();
        f16x8 af[4], bfv[4];
        #pragma unroll
        for (int mi = 0; mi < 4; ++mi)
            af[mi] = *(const f16x8*)(&As[(wm*64 + mi*16 + r) * 32 + 8 * g]);
        #pragma unroll
        for (int ni = 0; ni < 4; ++ni)
            bfv[ni] = *(const f16x8*)(&Bs[(wn*64 + ni*16 + r) * 32 + 8 * g]);
        #pragma unroll
        for (int mi = 0; mi < 4; ++mi)
            #pragma unroll
            for (int ni = 0; ni < 4; ++ni)
                acc[mi][ni] = __builtin_amdgcn_mfma_f32_16x16x32_f16(
                                  af[mi], bfv[ni], acc[mi][ni], 0, 0, 0);
    }
    #pragma unroll
    for (int mi = 0; mi < 4; ++mi)
        #pragma unroll
        for (int ni = 0; ni < 4; ++ni)
            #pragma unroll
            for (int j = 0; j < 4; ++j)
                C[(size_t)(by*128 + wm*64 + mi*16 + 4*g + j) * 1024
                  + bx*128 + wn*64 + ni*16 + r] = acc[mi][ni][j];
}

// ---------------- launch ----------------

extern "C" void kernel_launch(void* const* d_in, const int* in_sizes, int n_in,
                              void* d_out, int out_size, void* d_ws, size_t ws_size,
                              hipStream_t stream) {
    const float* q = (const float*)d_in[0];
    const float* k = (const float*)d_in[1];
    const float* v = (const float*)d_in[2];
    const float* w = (const float*)d_in[3];
    float* out = (float*)d_out;

    char* ws = (char*)d_ws;                       // needs 22 MiB
    _Float16* Qr = (_Float16*)(ws);
    _Float16* Kr = (_Float16*)(ws + ((size_t)8  << 20));
    _Float16* Vt = (_Float16*)(ws + ((size_t)10 << 20));
    _Float16* Wt = (_Float16*)(ws + ((size_t)12 << 20));
    _Float16* AO = (_Float16*)(ws + ((size_t)14 << 20));

    hipLaunchKernelGGL(rope_q_kernel, dim3(8192), dim3(256), 0, stream, q, Qr);
    hipLaunchKernelGGL(rope_k_kernel, dim3(2048), dim3(256), 0, stream, k, Kr);
    hipLaunchKernelGGL(prep_v_kernel, dim3(4096), dim3(256), 0, stream, v, Vt);
    hipLaunchKernelGGL(prep_w_kernel, dim3(4096), dim3(256), 0, stream, w, Wt);
    hipLaunchKernelGGL(attn_kernel,   dim3(1024), dim3(256), 0, stream, Qr, Kr, Vt, AO);
    hipLaunchKernelGGL(gemm_kernel,   dim3(8, 32), dim3(256), 0, stream, AO, Wt, out);
}

// Round 3
// 86.510 us; speedup vs baseline: 4.3808x; 1.1125x over previous
//
#include <hip/hip_runtime.h>
#include <math.h>

#define T_SEQ 2048
#define NH    16
#define NKV   4
// ws layout: tb (sin/cos table, 512KB) @0 ; Kr f16 @1MB (2MB) ; Vt f16 @3MB (2MB) ;
//            Wt f16 @5MB (2MB) ; AO f16 @7MB (8MB). Total 15MB.

typedef __attribute__((ext_vector_type(8))) _Float16 f16x8;
typedef __attribute__((ext_vector_type(4))) _Float16 f16x4;
typedef __attribute__((ext_vector_type(4))) float    f32x4;

// ---------------- sin/cos table: tb[t*32+i] = {cos, sin}(t * 10000^(-i/32)) ----
__global__ __launch_bounds__(256) void table_kernel(float2* __restrict__ tb)
{
    int idx = blockIdx.x * 256 + threadIdx.x;     // [0, 2048*32)
    int i = idx & 31, t = idx >> 5;
    float inv = __expf((float)i * (-9.210340371976184f / 32.0f));
    float ang = (float)t * inv;
    tb[idx] = make_float2(cosf(ang), sinf(ang));  // libm: proper range reduction
}

// ---------------- K RoPE (table-driven) ----------------
__global__ __launch_bounds__(256) void rope_k_kernel(const float* __restrict__ k,
                                                     const float2* __restrict__ tb,
                                                     _Float16* __restrict__ Kr)
{
    int idx = blockIdx.x * 256 + threadIdx.x;     // [0, 2*4*2048*32)
    int i   = idx & 31;
    int t   = (idx >> 5) & 2047;
    int bk  = idx >> 16;                          // b*4+kh
    float2 cs = tb[t * 32 + i];
    const float* src = k + ((size_t)(bk >> 2) * T_SEQ + t) * 256 + (bk & 3) * 64 + i;
    float x1 = src[0], x2 = src[32];
    _Float16* dst = Kr + ((size_t)bk * T_SEQ + t) * 64 + i;
    dst[0]  = (_Float16)(x1 * cs.x - x2 * cs.y);
    dst[32] = (_Float16)(x2 * cs.x + x1 * cs.y);
}

// ---------------- V transpose via LDS (both sides coalesced) ----------------
__global__ __launch_bounds__(256) void prep_v_kernel(const float* __restrict__ v,
                                                     _Float16* __restrict__ Vt)
{
    __shared__ _Float16 L[64 * 72];
    const int t0 = blockIdx.x * 64, bk = blockIdx.y;
    const int b = bk >> 2, kh = bk & 3;
    const int rr = threadIdx.x >> 2, pp = threadIdx.x & 3;
    const float* src = v + ((size_t)(b * T_SEQ + t0 + rr)) * 256 + kh * 64 + pp * 16;
    f32x4 s0 = *(const f32x4*)(src), s1 = *(const f32x4*)(src + 4);
    f32x4 s2 = *(const f32x4*)(src + 8), s3 = *(const f32x4*)(src + 12);
    _Float16* lp = &L[rr * 72 + pp * 16];
    #pragma unroll
    for (int j = 0; j < 4; ++j) { lp[j] = (_Float16)s0[j]; lp[4+j] = (_Float16)s1[j];
                                  lp[8+j] = (_Float16)s2[j]; lp[12+j] = (_Float16)s3[j]; }
    __syncthreads();
    f16x8 w0, w1;
    #pragma unroll
    for (int j = 0; j < 8; ++j) w0[j] = L[(pp * 16 + j) * 72 + rr];
    #pragma unroll
    for (int j = 0; j < 8; ++j) w1[j] = L[(pp * 16 + 8 + j) * 72 + rr];
    _Float16* dst = Vt + ((size_t)bk * 64 + rr) * T_SEQ + t0 + pp * 16;
    *(f16x8*)dst = w0; *(f16x8*)(dst + 8) = w1;
}

// ---------------- W transpose via LDS ----------------
__global__ __launch_bounds__(256) void prep_w_kernel(const float* __restrict__ w,
                                                     _Float16* __restrict__ Wt)
{
    __shared__ _Float16 L[64 * 72];
    const int k0 = blockIdx.x * 64, n0 = blockIdx.y * 64;
    const int rr = threadIdx.x >> 2, pp = threadIdx.x & 3;
    const float* src = w + (size_t)(k0 + rr) * 1024 + n0 + pp * 16;
    f32x4 s0 = *(const f32x4*)(src), s1 = *(const f32x4*)(src + 4);
    f32x4 s2 = *(const f32x4*)(src + 8), s3 = *(const f32x4*)(src + 12);
    _Float16* lp = &L[rr * 72 + pp * 16];
    #pragma unroll
    for (int j = 0; j < 4; ++j) { lp[j] = (_Float16)s0[j]; lp[4+j] = (_Float16)s1[j];
                                  lp[8+j] = (_Float16)s2[j]; lp[12+j] = (_Float16)s3[j]; }
    __syncthreads();
    f16x8 w0, w1;
    #pragma unroll
    for (int j = 0; j < 8; ++j) w0[j] = L[(pp * 16 + j) * 72 + rr];
    #pragma unroll
    for (int j = 0; j < 8; ++j) w1[j] = L[(pp * 16 + 8 + j) * 72 + rr];
    _Float16* dst = Wt + (size_t)(n0 + rr) * 1024 + k0 + pp * 16;
    *(f16x8*)dst = w0; *(f16x8*)(dst + 8) = w1;
}

// ---------------- flash attention, causal-paired q-blocks ----------------
// Block = 4 waves handles q-block PAIR (p, 31-p): uniform 33 MFMA-tile-units per
// block. Each wave: 16 rows of each tile; K/V LDS frags shared by both tiles.
// Swapped QK^T; inline Q-RoPE from table; defer-rescale (THR=8); LDS-bounced
// epilogue for coalesced AO stores.

__global__ __launch_bounds__(256) void attn_kernel(const float* __restrict__ q,
                                                   const float2* __restrict__ tb,
                                                   const _Float16* __restrict__ Kr,
                                                   const _Float16* __restrict__ Vt,
                                                   _Float16* __restrict__ AO)
{
    __shared__ _Float16 smem[16384];              // Ks[2]|Vs[2]; reused as Os[2]

    const int wid  = threadIdx.x >> 6;
    const int lane = threadIdx.x & 63;
    const int bh = blockIdx.x & 31;               // b*16+h
    const int p  = blockIdx.x >> 5;               // pair id, longest stream first
    const int qb0 = p, qb1 = 31 - p;
    const int b = bh >> 4, h = bh & 15;
    const int kh = h >> 2;
    const int bkh = b * NKV + kh;
    const int g = lane >> 4, r = lane & 15;

    // staging geometry (each wave stages 16 rows of K and of V per tile)
    const int srow   = wid * 16 + (lane >> 3);
    const int schunk = lane & 7;
    const _Float16* kgbase = Kr + (size_t)bkh * T_SEQ * 64;
    const _Float16* vgbase = Vt + (size_t)bkh * 64 * T_SEQ;
    const int kd0 = srow * 64 + ((schunk ^ (srow & 7)) * 8);
    const int kd1 = kd0 + 8 * 64;

    // prologue global loads first (hide under RoPE math)
    f16x8 stK0, stK1, stV0, stV1;
    {
        const _Float16* kg = kgbase + (size_t)srow * 64 + schunk * 8;
        stK0 = *(const f16x8*)(kg);
        stK1 = *(const f16x8*)(kg + 8 * 64);
        const _Float16* vg = vgbase + (size_t)srow * T_SEQ + schunk * 8;
        stV0 = *(const f16x8*)(vg);
        stV1 = *(const f16x8*)(vg + 8 * T_SEQ);
    }

    // inline RoPE'd Q fragments for both tiles (pre-scaled by 1/8)
    f16x8 qa[2][2];
    #pragma unroll
    for (int tl = 0; tl < 2; ++tl) {
        const int t = (tl ? qb1 : qb0) * 64 + wid * 16 + r;
        const float* qs = q + ((size_t)b * T_SEQ + t) * 1024 + h * 64 + 8 * g;
        const float2* tp = tb + t * 32 + 8 * g;
        #pragma unroll
        for (int j = 0; j < 8; ++j) {
            float x0 = qs[j], x1 = qs[32 + j];
            float2 cs = tp[j];
            qa[tl][0][j] = (_Float16)((x0 * cs.x - x1 * cs.y) * 0.125f);
            qa[tl][1][j] = (_Float16)((x1 * cs.x + x0 * cs.y) * 0.125f);
        }
    }

    *(f16x8*)(&smem[kd0])        = stK0;          // Ks[0]
    *(f16x8*)(&smem[kd1])        = stK1;
    *(f16x8*)(&smem[8192 + kd0]) = stV0;          // Vs[0]
    *(f16x8*)(&smem[8192 + kd1]) = stV1;
    __syncthreads();

    f32x4 o[2][4];
    #pragma unroll
    for (int tl = 0; tl < 2; ++tl)
        #pragma unroll
        for (int db = 0; db < 4; ++db) o[tl][db] = (f32x4){0.f,0.f,0.f,0.f};
    float mrun[2] = {-INFINITY, -INFINITY};
    float lsum[2] = {0.f, 0.f};
    int cur = 0;

    for (int kvb = 0; kvb <= qb1; ++kvb) {
        const bool hasNext = (kvb < qb1);
        if (hasNext) {
            const int nb = (kvb + 1) * 64;
            const _Float16* kg = kgbase + (size_t)(nb + srow) * 64 + schunk * 8;
            stK0 = *(const f16x8*)(kg);
            stK1 = *(const f16x8*)(kg + 8 * 64);
            const _Float16* vg = vgbase + (size_t)srow * T_SEQ + nb + schunk * 8;
            stV0 = *(const f16x8*)(vg);
            stV1 = *(const f16x8*)(vg + 8 * T_SEQ);
        }
        const bool act0 = (kvb <= qb0);
        const _Float16* ks = smem + cur * 4096;
        const _Float16* vs = smem + 8192 + cur * 4096;

        // ---- QK^T (K frags shared by both q-tiles) ----
        f32x4 stt[2][4];
        __builtin_amdgcn_s_setprio(1);
        #pragma unroll
        for (int kt = 0; kt < 4; ++kt) {
            f16x8 ka0 = *(const f16x8*)(ks + (kt*16 + r) * 64 + ((g       ^ (r & 7)) * 8));
            f16x8 ka1 = *(const f16x8*)(ks + (kt*16 + r) * 64 + (((4 + g) ^ (r & 7)) * 8));
            f32x4 s1 = {0.f,0.f,0.f,0.f};
            s1 = __builtin_amdgcn_mfma_f32_16x16x32_f16(ka0, qa[1][0], s1, 0, 0, 0);
            s1 = __builtin_amdgcn_mfma_f32_16x16x32_f16(ka1, qa[1][1], s1, 0, 0, 0);
            stt[1][kt] = s1;
            if (act0) {
                f32x4 s0 = {0.f,0.f,0.f,0.f};
                s0 = __builtin_amdgcn_mfma_f32_16x16x32_f16(ka0, qa[0][0], s0, 0, 0, 0);
                s0 = __builtin_amdgcn_mfma_f32_16x16x32_f16(ka1, qa[0][1], s0, 0, 0, 0);
                stt[0][kt] = s0;
            }
        }
        __builtin_amdgcn_s_setprio(0);

        // ---- causal masking on diagonal iterations ----
        if (kvb == qb0) {
            #pragma unroll
            for (int kt = 0; kt < 4; ++kt)
                #pragma unroll
                for (int j = 0; j < 4; ++j)
                    if (kt*16 + 4*g + j > wid*16 + r) stt[0][kt][j] = -1e9f;
        }
        if (kvb == qb1) {
            #pragma unroll
            for (int kt = 0; kt < 4; ++kt)
                #pragma unroll
                for (int j = 0; j < 4; ++j)
                    if (kt*16 + 4*g + j > wid*16 + r) stt[1][kt][j] = -1e9f;
        }

        // ---- online softmax per tile (defer-rescale, THR=8) ----
        f16x4 pf[2][4];
        #pragma unroll
        for (int tl = 0; tl < 2; ++tl) {
            if (tl == 0 && !act0) continue;
            float pm = -1e9f;
            #pragma unroll
            for (int kt = 0; kt < 4; ++kt)
                pm = fmaxf(pm, fmaxf(fmaxf(stt[tl][kt][0], stt[tl][kt][1]),
                                     fmaxf(stt[tl][kt][2], stt[tl][kt][3])));
            pm = fmaxf(pm, __shfl_xor(pm, 16));
            pm = fmaxf(pm, __shfl_xor(pm, 32));
            if (!__all(pm <= mrun[tl] + 8.0f)) {
                float mn   = fmaxf(mrun[tl], pm);
                float corr = __expf(mrun[tl] - mn);
                lsum[tl] *= corr;
                mrun[tl]  = mn;
                f32x4 cf = { __shfl(corr, 4*g + 0), __shfl(corr, 4*g + 1),
                             __shfl(corr, 4*g + 2), __shfl(corr, 4*g + 3) };
                o[tl][0] *= cf; o[tl][1] *= cf; o[tl][2] *= cf; o[tl][3] *= cf;
            }
            float ps = 0.0f;
            #pragma unroll
            for (int kt = 0; kt < 4; ++kt) {
                float p0 = __expf(stt[tl][kt][0] - mrun[tl]);
                float p1 = __expf(stt[tl][kt][1] - mrun[tl]);
                float p2 = __expf(stt[tl][kt][2] - mrun[tl]);
                float p3 = __expf(stt[tl][kt][3] - mrun[tl]);
                ps += (p0 + p1) + (p2 + p3);
                pf[tl][kt] = (f16x4){(_Float16)p0, (_Float16)p1,
                                     (_Float16)p2, (_Float16)p3};
            }
            ps += __shfl_xor(ps, 16);
            ps += __shfl_xor(ps, 32);
            lsum[tl] += ps;
        }

        // ---- PV (V frags shared by both q-tiles) ----
        __builtin_amdgcn_s_setprio(1);
        #pragma unroll
        for (int kt = 0; kt < 4; ++kt) {
            const int vc = ((2*kt + (g >> 1)) ^ (r & 7)) * 8 + (g & 1) * 4;
            f16x4 v0 = *(const f16x4*)(vs + (0*16 + r) * 64 + vc);
            f16x4 v1 = *(const f16x4*)(vs + (1*16 + r) * 64 + vc);
            f16x4 v2 = *(const f16x4*)(vs + (2*16 + r) * 64 + vc);
            f16x4 v3 = *(const f16x4*)(vs + (3*16 + r) * 64 + vc);
            o[1][0] = __builtin_amdgcn_mfma_f32_16x16x16f16(pf[1][kt], v0, o[1][0], 0, 0, 0);
            o[1][1] = __builtin_amdgcn_mfma_f32_16x16x16f16(pf[1][kt], v1, o[1][1], 0, 0, 0);
            o[1][2] = __builtin_amdgcn_mfma_f32_16x16x16f16(pf[1][kt], v2, o[1][2], 0, 0, 0);
            o[1][3] = __builtin_amdgcn_mfma_f32_16x16x16f16(pf[1][kt], v3, o[1][3], 0, 0, 0);
            if (act0) {
                o[0][0] = __builtin_amdgcn_mfma_f32_16x16x16f16(pf[0][kt], v0, o[0][0], 0, 0, 0);
                o[0][1] = __builtin_amdgcn_mfma_f32_16x16x16f16(pf[0][kt], v1, o[0][1], 0, 0, 0);
                o[0][2] = __builtin_amdgcn_mfma_f32_16x16x16f16(pf[0][kt], v2, o[0][2], 0, 0, 0);
                o[0][3] = __builtin_amdgcn_mfma_f32_16x16x16f16(pf[0][kt], v3, o[0][3], 0, 0, 0);
            }
        }
        __builtin_amdgcn_s_setprio(0);

        if (hasNext) {
            _Float16* kw = smem + (cur ^ 1) * 4096;
            _Float16* vw = smem + 8192 + (cur ^ 1) * 4096;
            *(f16x8*)(&kw[kd0]) = stK0;
            *(f16x8*)(&kw[kd1]) = stK1;
            *(f16x8*)(&vw[kd0]) = stV0;
            *(f16x8*)(&vw[kd1]) = stV1;
            cur ^= 1;
        }
        __syncthreads();
    }

    // ---- epilogue: normalize, bounce through LDS, coalesced AO stores ----
    #pragma unroll
    for (int tl = 0; tl < 2; ++tl) {
        f32x4 li = { 1.0f / __shfl(lsum[tl], 4*g + 0), 1.0f / __shfl(lsum[tl], 4*g + 1),
                     1.0f / __shfl(lsum[tl], 4*g + 2), 1.0f / __shfl(lsum[tl], 4*g + 3) };
        _Float16* Os = smem + tl * 4608;          // [64][72] f16
        #pragma unroll
        for (int db = 0; db < 4; ++db) {
            f32x4 ov = o[tl][db] * li;
            #pragma unroll
            for (int j = 0; j < 4; ++j)
                Os[(wid*16 + 4*g + j) * 72 + db*16 + r] = (_Float16)ov[j];
        }
    }
    __syncthreads();
    {
        const int row = threadIdx.x >> 2, part = threadIdx.x & 3;
        #pragma unroll
        for (int tl = 0; tl < 2; ++tl) {
            const int qb = tl ? qb1 : qb0;
            const _Float16* src = smem + tl * 4608 + row * 72 + part * 16;
            _Float16* dst = AO + ((size_t)b * T_SEQ + qb * 64 + row) * 1024 + h * 64 + part * 16;
            *(f16x8*)dst       = *(const f16x8*)src;
            *(f16x8*)(dst + 8) = *(const f16x8*)(src + 8);
        }
    }
}

// ---------------- projection GEMM: out[4096][1024] = AO * Wt^T ----------------
// 128x128 tile, BK=32, double-buffered LDS (1 barrier/iter), XCD-friendly map.

__global__ __launch_bounds__(256) void gemm_kernel(const _Float16* __restrict__ A,
                                                   const _Float16* __restrict__ Bt,
                                                   float* __restrict__ C)
{
    __shared__ _Float16 As[2][128 * 32];
    __shared__ _Float16 Bs[2][128 * 32];
    const int tid  = threadIdx.x;
    const int bx   = blockIdx.x >> 5;             // n-tile 0..7
    const int by   = blockIdx.x & 31;             // m-tile 0..31 (same-by -> same XCD)
    const int lane = tid & 63;
    const int wid  = tid >> 6;
    const int g = lane >> 4, r = lane & 15;
    const int wm = wid >> 1, wn = wid & 1;

    f32x4 acc[4][4];
    #pragma unroll
    for (int i = 0; i < 4; ++i)
        #pragma unroll
        for (int j = 0; j < 4; ++j) acc[i][j] = (f32x4){0.f,0.f,0.f,0.f};

    const int c0 = tid, c1 = tid + 256;
    const size_t a0off = (size_t)(by*128 + (c0 >> 2)) * 1024 + (c0 & 3) * 8;
    const size_t a1off = (size_t)(by*128 + (c1 >> 2)) * 1024 + (c1 & 3) * 8;
    const size_t b0off = (size_t)(bx*128 + (c0 >> 2)) * 1024 + (c0 & 3) * 8;
    const size_t b1off = (size_t)(bx*128 + (c1 >> 2)) * 1024 + (c1 & 3) * 8;

    f16x8 a0 = *(const f16x8*)(A  + a0off);
    f16x8 a1 = *(const f16x8*)(A  + a1off);
    f16x8 b0 = *(const f16x8*)(Bt + b0off);
    f16x8 b1 = *(const f16x8*)(Bt + b1off);
    *(f16x8*)(&As[0][c0 * 8]) = a0;
    *(f16x8*)(&As[0][c1 * 8]) = a1;
    *(f16x8*)(&Bs[0][c0 * 8]) = b0;
    *(f16x8*)(&Bs[0][c1 * 8]) = b1;
    __syncthreads();
    int cur = 0;

    for (int kt = 0; kt < 32; ++kt) {
        if (kt < 31) {
            a0 = *(const f16x8*)(A  + a0off + (kt+1) * 32);
            a1 = *(const f16x8*)(A  + a1off + (kt+1) * 32);
            b0 = *(const f16x8*)(Bt + b0off + (kt+1) * 32);
            b1 = *(const f16x8*)(Bt + b1off + (kt+1) * 32);
        }
        f16x8 af[4], bfv[4];
        #pragma unroll
        for (int mi = 0; mi < 4; ++mi)
            af[mi] = *(const f16x8*)(&As[cur][(wm*64 + mi*16 + r) * 32 + 8 * g]);
        #pragma unroll
        for (int ni = 0; ni < 4; ++ni)
            bfv[ni] = *(const f16x8*)(&Bs[cur][(wn*64 + ni*16 + r) * 32 + 8 * g]);
        __builtin_amdgcn_s_setprio(1);
        #pragma unroll
        for (int mi = 0; mi < 4; ++mi)
            #pragma unroll
            for (int ni = 0; ni < 4; ++ni)
                acc[mi][ni] = __builtin_amdgcn_mfma_f32_16x16x32_f16(
                                  af[mi], bfv[ni], acc[mi][ni], 0, 0, 0);
        __builtin_amdgcn_s_setprio(0);
        if (kt < 31) {
            *(f16x8*)(&As[cur ^ 1][c0 * 8]) = a0;
            *(f16x8*)(&As[cur ^ 1][c1 * 8]) = a1;
            *(f16x8*)(&Bs[cur ^ 1][c0 * 8]) = b0;
            *(f16x8*)(&Bs[cur ^ 1][c1 * 8]) = b1;
            cur ^= 1;
        }
        __syncthreads();
    }
    #pragma unroll
    for (int mi = 0; mi < 4; ++mi)
        #pragma unroll
        for (int ni = 0; ni < 4; ++ni)
            #pragma unroll
            for (int j = 0; j < 4; ++j)
                C[(size_t)(by*128 + wm*64 + mi*16 + 4*g + j) * 1024
                  + bx*128 + wn*64 + ni*16 + r] = acc[mi][ni][j];
}

// ---------------- launch ----------------

extern "C" void kernel_launch(void* const* d_in, const int* in_sizes, int n_in,
                              void* d_out, int out_size, void* d_ws, size_t ws_size,
                              hipStream_t stream) {
    const float* q = (const float*)d_in[0];
    const float* k = (const float*)d_in[1];
    const float* v = (const float*)d_in[2];
    const float* w = (const float*)d_in[3];
    float* out = (float*)d_out;

    char* ws = (char*)d_ws;                       // needs 15 MiB
    float2*   tb = (float2*)(ws);
    _Float16* Kr = (_Float16*)(ws + ((size_t)1 << 20));
    _Float16* Vt = (_Float16*)(ws + ((size_t)3 << 20));
    _Float16* Wt = (_Float16*)(ws + ((size_t)5 << 20));
    _Float16* AO = (_Float16*)(ws + ((size_t)7 << 20));

    hipLaunchKernelGGL(table_kernel,  dim3(256),     dim3(256), 0, stream, tb);
    hipLaunchKernelGGL(rope_k_kernel, dim3(2048),    dim3(256), 0, stream, k, tb, Kr);
    hipLaunchKernelGGL(prep_v_kernel, dim3(32, 8),   dim3(256), 0, stream, v, Vt);
    hipLaunchKernelGGL(prep_w_kernel, dim3(16, 16),  dim3(256), 0, stream, w, Wt);
    hipLaunchKernelGGL(attn_kernel,   dim3(512),     dim3(256), 0, stream, q, tb, Kr, Vt, AO);
    hipLaunchKernelGGL(gemm_kernel,   dim3(256),     dim3(256), 0, stream, AO, Wt, out);
}

// Round 4
// 76.721 us; speedup vs baseline: 4.9398x; 1.1276x over previous
//
#include <hip/hip_runtime.h>
#include <math.h>

#define T_SEQ 2048
#define NH    16
#define NKV   4
// ws layout: tb (sin/cos table, 512KB) @0 ; Kr f16 @1MB (2MB) ; Vt f16 @3MB (2MB) ;
//            Wt f16 @5MB (2MB) ; AO f16 @7MB (8MB). Total 15MB.

typedef __attribute__((ext_vector_type(8))) _Float16 f16x8;
typedef __attribute__((ext_vector_type(4))) _Float16 f16x4;
typedef __attribute__((ext_vector_type(4))) float    f32x4;

// ---------------- fused prep: table | rope_k | V-transpose | W-transpose ------
__global__ __launch_bounds__(256) void prep_kernel(const float* __restrict__ k,
                                                   const float* __restrict__ v,
                                                   const float* __restrict__ w,
                                                   float2* __restrict__ tb,
                                                   _Float16* __restrict__ Kr,
                                                   _Float16* __restrict__ Vt,
                                                   _Float16* __restrict__ Wt)
{
    __shared__ _Float16 L[64 * 72];
    const int bx = blockIdx.x;
    if (bx < 256) {
        // sin/cos table: tb[t*32+i] = {cos, sin}(t * 10000^(-i/32))
        int idx = bx * 256 + threadIdx.x;
        int i = idx & 31, t = idx >> 5;
        float inv = __expf((float)i * (-9.210340371976184f / 32.0f));
        float ang = (float)t * inv;
        tb[idx] = make_float2(cosf(ang), sinf(ang));
    } else if (bx < 2304) {
        // K RoPE (inline trig; independent of tb)
        int idx = (bx - 256) * 256 + threadIdx.x;     // [0, 2*4*2048*32)
        int i   = idx & 31;
        int t   = (idx >> 5) & 2047;
        int bk  = idx >> 16;                          // b*4+kh
        float inv = __expf((float)i * (-9.210340371976184f / 32.0f));
        float ang = (float)t * inv;
        float sn = sinf(ang), cs = cosf(ang);
        const float* src = k + ((size_t)(bk >> 2) * T_SEQ + t) * 256 + (bk & 3) * 64 + i;
        float x1 = src[0], x2 = src[32];
        _Float16* dst = Kr + ((size_t)bk * T_SEQ + t) * 64 + i;
        dst[0]  = (_Float16)(x1 * cs - x2 * sn);
        dst[32] = (_Float16)(x2 * cs + x1 * sn);
    } else if (bx < 2560) {
        // V transpose via LDS (both sides coalesced)
        const int id = bx - 2304;                     // 32 t-tiles x 8 bk
        const int t0 = (id & 31) * 64, bk = id >> 5;
        const int b = bk >> 2, kh = bk & 3;
        const int rr = threadIdx.x >> 2, pp = threadIdx.x & 3;
        const float* src = v + ((size_t)(b * T_SEQ + t0 + rr)) * 256 + kh * 64 + pp * 16;
        f32x4 s0 = *(const f32x4*)(src), s1 = *(const f32x4*)(src + 4);
        f32x4 s2 = *(const f32x4*)(src + 8), s3 = *(const f32x4*)(src + 12);
        _Float16* lp = &L[rr * 72 + pp * 16];
        #pragma unroll
        for (int j = 0; j < 4; ++j) { lp[j] = (_Float16)s0[j]; lp[4+j] = (_Float16)s1[j];
                                      lp[8+j] = (_Float16)s2[j]; lp[12+j] = (_Float16)s3[j]; }
        __syncthreads();
        f16x8 w0, w1;
        #pragma unroll
        for (int j = 0; j < 8; ++j) w0[j] = L[(pp * 16 + j) * 72 + rr];
        #pragma unroll
        for (int j = 0; j < 8; ++j) w1[j] = L[(pp * 16 + 8 + j) * 72 + rr];
        _Float16* dst = Vt + ((size_t)bk * 64 + rr) * T_SEQ + t0 + pp * 16;
        *(f16x8*)dst = w0; *(f16x8*)(dst + 8) = w1;
    } else {
        // W transpose via LDS
        const int id = bx - 2560;                     // 16 k-tiles x 16 n-tiles
        const int k0 = (id & 15) * 64, n0 = (id >> 4) * 64;
        const int rr = threadIdx.x >> 2, pp = threadIdx.x & 3;
        const float* src = w + (size_t)(k0 + rr) * 1024 + n0 + pp * 16;
        f32x4 s0 = *(const f32x4*)(src), s1 = *(const f32x4*)(src + 4);
        f32x4 s2 = *(const f32x4*)(src + 8), s3 = *(const f32x4*)(src + 12);
        _Float16* lp = &L[rr * 72 + pp * 16];
        #pragma unroll
        for (int j = 0; j < 4; ++j) { lp[j] = (_Float16)s0[j]; lp[4+j] = (_Float16)s1[j];
                                      lp[8+j] = (_Float16)s2[j]; lp[12+j] = (_Float16)s3[j]; }
        __syncthreads();
        f16x8 w0, w1;
        #pragma unroll
        for (int j = 0; j < 8; ++j) w0[j] = L[(pp * 16 + j) * 72 + rr];
        #pragma unroll
        for (int j = 0; j < 8; ++j) w1[j] = L[(pp * 16 + 8 + j) * 72 + rr];
        _Float16* dst = Wt + (size_t)(n0 + rr) * 1024 + k0 + pp * 16;
        *(f16x8*)dst = w0; *(f16x8*)(dst + 8) = w1;
    }
}

// ---------------- flash attention, causal-paired q-blocks ----------------
// Block = 4 waves handles q-block PAIR (p, 31-p): uniform 33 MFMA-tile-units.
// Swapped QK^T; inline Q-RoPE; K/V LDS frags shared by both tiles; row-sum via
// ones-column MFMA (o4); lane-local defer-rescale check; LDS-bounced epilogue.

__global__ __launch_bounds__(256) void attn_kernel(const float* __restrict__ q,
                                                   const float2* __restrict__ tb,
                                                   const _Float16* __restrict__ Kr,
                                                   const _Float16* __restrict__ Vt,
                                                   _Float16* __restrict__ AO)
{
    __shared__ _Float16 smem[16384];              // Ks[2]|Vs[2]; reused as Os[2]

    const int wid  = threadIdx.x >> 6;
    const int lane = threadIdx.x & 63;
    const int bh = blockIdx.x & 31;               // b*16+h
    const int p  = blockIdx.x >> 5;               // pair id
    const int qb0 = p, qb1 = 31 - p;
    const int b = bh >> 4, h = bh & 15;
    const int kh = h >> 2;
    const int bkh = b * NKV + kh;
    const int g = lane >> 4, r = lane & 15;

    const int srow   = wid * 16 + (lane >> 3);
    const int schunk = lane & 7;
    const _Float16* kgbase = Kr + (size_t)bkh * T_SEQ * 64;
    const _Float16* vgbase = Vt + (size_t)bkh * 64 * T_SEQ;
    const int kd0 = srow * 64 + ((schunk ^ (srow & 7)) * 8);
    const int kd1 = kd0 + 8 * 64;

    f16x8 stK0, stK1, stV0, stV1;
    {
        const _Float16* kg = kgbase + (size_t)srow * 64 + schunk * 8;
        stK0 = *(const f16x8*)(kg);
        stK1 = *(const f16x8*)(kg + 8 * 64);
        const _Float16* vg = vgbase + (size_t)srow * T_SEQ + schunk * 8;
        stV0 = *(const f16x8*)(vg);
        stV1 = *(const f16x8*)(vg + 8 * T_SEQ);
    }

    // inline RoPE'd Q fragments for both tiles (pre-scaled by 1/8)
    f16x8 qa[2][2];
    #pragma unroll
    for (int tl = 0; tl < 2; ++tl) {
        const int t = (tl ? qb1 : qb0) * 64 + wid * 16 + r;
        const float* qs = q + ((size_t)b * T_SEQ + t) * 1024 + h * 64 + 8 * g;
        const float2* tp = tb + t * 32 + 8 * g;
        #pragma unroll
        for (int j = 0; j < 8; ++j) {
            float x0 = qs[j], x1 = qs[32 + j];
            float2 cs = tp[j];
            qa[tl][0][j] = (_Float16)((x0 * cs.x - x1 * cs.y) * 0.125f);
            qa[tl][1][j] = (_Float16)((x1 * cs.x + x0 * cs.y) * 0.125f);
        }
    }

    *(f16x8*)(&smem[kd0])        = stK0;          // Ks[0]
    *(f16x8*)(&smem[kd1])        = stK1;
    *(f16x8*)(&smem[8192 + kd0]) = stV0;          // Vs[0]
    *(f16x8*)(&smem[8192 + kd1]) = stV1;
    __syncthreads();

    f32x4 o[2][4];
    f32x4 o4[2];                                   // row-sum accumulators (ones-col)
    #pragma unroll
    for (int tl = 0; tl < 2; ++tl) {
        #pragma unroll
        for (int db = 0; db < 4; ++db) o[tl][db] = (f32x4){0.f,0.f,0.f,0.f};
        o4[tl] = (f32x4){0.f,0.f,0.f,0.f};
    }
    const f16x4 onesf = {(_Float16)1.f, (_Float16)1.f, (_Float16)1.f, (_Float16)1.f};
    float mrun[2] = {-INFINITY, -INFINITY};
    int cur = 0;

    for (int kvb = 0; kvb <= qb1; ++kvb) {
        const bool hasNext = (kvb < qb1);
        if (hasNext) {
            const int nb = (kvb + 1) * 64;
            const _Float16* kg = kgbase + (size_t)(nb + srow) * 64 + schunk * 8;
            stK0 = *(const f16x8*)(kg);
            stK1 = *(const f16x8*)(kg + 8 * 64);
            const _Float16* vg = vgbase + (size_t)srow * T_SEQ + nb + schunk * 8;
            stV0 = *(const f16x8*)(vg);
            stV1 = *(const f16x8*)(vg + 8 * T_SEQ);
        }
        const bool act0 = (kvb <= qb0);
        const _Float16* ks = smem + cur * 4096;
        const _Float16* vs = smem + 8192 + cur * 4096;

        // ---- QK^T (K frags shared by both q-tiles) ----
        f32x4 stt[2][4];
        __builtin_amdgcn_s_setprio(1);
        #pragma unroll
        for (int kt = 0; kt < 4; ++kt) {
            f16x8 ka0 = *(const f16x8*)(ks + (kt*16 + r) * 64 + ((g       ^ (r & 7)) * 8));
            f16x8 ka1 = *(const f16x8*)(ks + (kt*16 + r) * 64 + (((4 + g) ^ (r & 7)) * 8));
            f32x4 s1 = {0.f,0.f,0.f,0.f};
            s1 = __builtin_amdgcn_mfma_f32_16x16x32_f16(ka0, qa[1][0], s1, 0, 0, 0);
            s1 = __builtin_amdgcn_mfma_f32_16x16x32_f16(ka1, qa[1][1], s1, 0, 0, 0);
            stt[1][kt] = s1;
            if (act0) {
                f32x4 s0 = {0.f,0.f,0.f,0.f};
                s0 = __builtin_amdgcn_mfma_f32_16x16x32_f16(ka0, qa[0][0], s0, 0, 0, 0);
                s0 = __builtin_amdgcn_mfma_f32_16x16x32_f16(ka1, qa[0][1], s0, 0, 0, 0);
                stt[0][kt] = s0;
            }
        }
        __builtin_amdgcn_s_setprio(0);

        // ---- causal masking on diagonal iterations ----
        if (kvb == qb0) {
            #pragma unroll
            for (int kt = 0; kt < 4; ++kt)
                #pragma unroll
                for (int j = 0; j < 4; ++j)
                    if (kt*16 + 4*g + j > wid*16 + r) stt[0][kt][j] = -1e9f;
        }
        if (kvb == qb1) {
            #pragma unroll
            for (int kt = 0; kt < 4; ++kt)
                #pragma unroll
                for (int j = 0; j < 4; ++j)
                    if (kt*16 + 4*g + j > wid*16 + r) stt[1][kt][j] = -1e9f;
        }

        // ---- online softmax (lane-local defer check; sum via MFMA below) ----
        f16x4 pf[2][4];
        #pragma unroll
        for (int tl = 0; tl < 2; ++tl) {
            if (tl == 0 && !act0) continue;
            float a0 = fmaxf(fmaxf(stt[tl][0][0], stt[tl][0][1]),
                             fmaxf(stt[tl][0][2], stt[tl][0][3]));
            float a1 = fmaxf(fmaxf(stt[tl][1][0], stt[tl][1][1]),
                             fmaxf(stt[tl][1][2], stt[tl][1][3]));
            float a2 = fmaxf(fmaxf(stt[tl][2][0], stt[tl][2][1]),
                             fmaxf(stt[tl][2][2], stt[tl][2][3]));
            float a3 = fmaxf(fmaxf(stt[tl][3][0], stt[tl][3][1]),
                             fmaxf(stt[tl][3][2], stt[tl][3][3]));
            float pmL = fmaxf(fmaxf(a0, a1), fmaxf(a2, a3));
            if (!__all(pmL <= mrun[tl] + 8.0f)) {   // rare: real max grew
                float pm = fmaxf(pmL, __shfl_xor(pmL, 16));
                pm = fmaxf(pm, __shfl_xor(pm, 32));
                float mn   = fmaxf(mrun[tl], pm);
                float corr = __expf(mrun[tl] - mn);
                mrun[tl]   = mn;
                f32x4 cf = { __shfl(corr, 4*g + 0), __shfl(corr, 4*g + 1),
                             __shfl(corr, 4*g + 2), __shfl(corr, 4*g + 3) };
                o[tl][0] *= cf; o[tl][1] *= cf; o[tl][2] *= cf; o[tl][3] *= cf;
                o4[tl]   *= cf;
            }
            #pragma unroll
            for (int kt = 0; kt < 4; ++kt) {
                float p0 = __expf(stt[tl][kt][0] - mrun[tl]);
                float p1 = __expf(stt[tl][kt][1] - mrun[tl]);
                float p2 = __expf(stt[tl][kt][2] - mrun[tl]);
                float p3 = __expf(stt[tl][kt][3] - mrun[tl]);
                pf[tl][kt] = (f16x4){(_Float16)p0, (_Float16)p1,
                                     (_Float16)p2, (_Float16)p3};
            }
        }

        // ---- PV + row-sum (V frags shared by both q-tiles) ----
        __builtin_amdgcn_s_setprio(1);
        #pragma unroll
        for (int kt = 0; kt < 4; ++kt) {
            const int vc = ((2*kt + (g >> 1)) ^ (r & 7)) * 8 + (g & 1) * 4;
            f16x4 v0 = *(const f16x4*)(vs + (0*16 + r) * 64 + vc);
            f16x4 v1 = *(const f16x4*)(vs + (1*16 + r) * 64 + vc);
            f16x4 v2 = *(const f16x4*)(vs + (2*16 + r) * 64 + vc);
            f16x4 v3 = *(const f16x4*)(vs + (3*16 + r) * 64 + vc);
            o[1][0] = __builtin_amdgcn_mfma_f32_16x16x16f16(pf[1][kt], v0, o[1][0], 0, 0, 0);
            o[1][1] = __builtin_amdgcn_mfma_f32_16x16x16f16(pf[1][kt], v1, o[1][1], 0, 0, 0);
            o[1][2] = __builtin_amdgcn_mfma_f32_16x16x16f16(pf[1][kt], v2, o[1][2], 0, 0, 0);
            o[1][3] = __builtin_amdgcn_mfma_f32_16x16x16f16(pf[1][kt], v3, o[1][3], 0, 0, 0);
            o4[1]   = __builtin_amdgcn_mfma_f32_16x16x16f16(pf[1][kt], onesf, o4[1], 0, 0, 0);
            if (act0) {
                o[0][0] = __builtin_amdgcn_mfma_f32_16x16x16f16(pf[0][kt], v0, o[0][0], 0, 0, 0);
                o[0][1] = __builtin_amdgcn_mfma_f32_16x16x16f16(pf[0][kt], v1, o[0][1], 0, 0, 0);
                o[0][2] = __builtin_amdgcn_mfma_f32_16x16x16f16(pf[0][kt], v2, o[0][2], 0, 0, 0);
                o[0][3] = __builtin_amdgcn_mfma_f32_16x16x16f16(pf[0][kt], v3, o[0][3], 0, 0, 0);
                o4[0]   = __builtin_amdgcn_mfma_f32_16x16x16f16(pf[0][kt], onesf, o4[0], 0, 0, 0);
            }
        }
        __builtin_amdgcn_s_setprio(0);

        if (hasNext) {
            _Float16* kw = smem + (cur ^ 1) * 4096;
            _Float16* vw = smem + 8192 + (cur ^ 1) * 4096;
            *(f16x8*)(&kw[kd0]) = stK0;
            *(f16x8*)(&kw[kd1]) = stK1;
            *(f16x8*)(&vw[kd0]) = stV0;
            *(f16x8*)(&vw[kd1]) = stV1;
            cur ^= 1;
        }
        __syncthreads();
    }

    // ---- epilogue: lane-local normalize, LDS bounce, coalesced AO stores ----
    #pragma unroll
    for (int tl = 0; tl < 2; ++tl) {
        f32x4 li;
        #pragma unroll
        for (int j = 0; j < 4; ++j) li[j] = 1.0f / o4[tl][j];
        _Float16* Os = smem + tl * 4608;          // [64][72] f16
        #pragma unroll
        for (int db = 0; db < 4; ++db) {
            f32x4 ov = o[tl][db] * li;
            #pragma unroll
            for (int j = 0; j < 4; ++j)
                Os[(wid*16 + 4*g + j) * 72 + db*16 + r] = (_Float16)ov[j];
        }
    }
    __syncthreads();
    {
        const int row = threadIdx.x >> 2, part = threadIdx.x & 3;
        #pragma unroll
        for (int tl = 0; tl < 2; ++tl) {
            const int qb = tl ? qb1 : qb0;
            const _Float16* src = smem + tl * 4608 + row * 72 + part * 16;
            _Float16* dst = AO + ((size_t)b * T_SEQ + qb * 64 + row) * 1024 + h * 64 + part * 16;
            *(f16x8*)dst       = *(const f16x8*)src;
            *(f16x8*)(dst + 8) = *(const f16x8*)(src + 8);
        }
    }
}

// ---------------- projection GEMM: out[4096][1024] = AO * Wt^T ----------------
// 128x64 tile (512 blocks -> 2 blocks/CU), BK=32, double-buffered LDS,
// padded stride 40 f16 to break the 8-way b128 read conflict.

#define AST 40
__global__ __launch_bounds__(256) void gemm_kernel(const _Float16* __restrict__ A,
                                                   const _Float16* __restrict__ Bt,
                                                   float* __restrict__ C)
{
    __shared__ _Float16 As[2][128 * AST];
    __shared__ _Float16 Bs[2][64 * AST];
    const int tid  = threadIdx.x;
    const int by   = blockIdx.x & 31;             // m-tile 0..31
    const int bx   = blockIdx.x >> 5;             // n-tile 0..15
    const int lane = tid & 63;
    const int wid  = tid >> 6;
    const int g = lane >> 4, r = lane & 15;
    const int wm = wid >> 1, wn = wid & 1;

    f32x4 acc[4][2];
    #pragma unroll
    for (int i = 0; i < 4; ++i)
        #pragma unroll
        for (int j = 0; j < 2; ++j) acc[i][j] = (f32x4){0.f,0.f,0.f,0.f};

    const int c0 = tid, c1 = tid + 256;           // A chunks (2/thread), B chunk (1)
    const size_t a0off = (size_t)(by*128 + (c0 >> 2)) * 1024 + (c0 & 3) * 8;
    const size_t a1off = (size_t)(by*128 + (c1 >> 2)) * 1024 + (c1 & 3) * 8;
    const size_t b0off = (size_t)(bx*64  + (c0 >> 2)) * 1024 + (c0 & 3) * 8;
    const int ad0 = (c0 >> 2) * AST + (c0 & 3) * 8;
    const int ad1 = (c1 >> 2) * AST + (c1 & 3) * 8;

    f16x8 a0 = *(const f16x8*)(A  + a0off);
    f16x8 a1 = *(const f16x8*)(A  + a1off);
    f16x8 b0 = *(const f16x8*)(Bt + b0off);
    *(f16x8*)(&As[0][ad0]) = a0;
    *(f16x8*)(&As[0][ad1]) = a1;
    *(f16x8*)(&Bs[0][ad0]) = b0;
    __syncthreads();
    int cur = 0;

    for (int kt = 0; kt < 32; ++kt) {
        if (kt < 31) {
            a0 = *(const f16x8*)(A  + a0off + (kt+1) * 32);
            a1 = *(const f16x8*)(A  + a1off + (kt+1) * 32);
            b0 = *(const f16x8*)(Bt + b0off + (kt+1) * 32);
        }
        f16x8 af[4], bfv[2];
        #pragma unroll
        for (int mi = 0; mi < 4; ++mi)
            af[mi] = *(const f16x8*)(&As[cur][(wm*64 + mi*16 + r) * AST + 8 * g]);
        #pragma unroll
        for (int ni = 0; ni < 2; ++ni)
            bfv[ni] = *(const f16x8*)(&Bs[cur][(wn*32 + ni*16 + r) * AST + 8 * g]);
        __builtin_amdgcn_s_setprio(1);
        #pragma unroll
        for (int mi = 0; mi < 4; ++mi)
            #pragma unroll
            for (int ni = 0; ni < 2; ++ni)
                acc[mi][ni] = __builtin_amdgcn_mfma_f32_16x16x32_f16(
                                  af[mi], bfv[ni], acc[mi][ni], 0, 0, 0);
        __builtin_amdgcn_s_setprio(0);
        if (kt < 31) {
            *(f16x8*)(&As[cur ^ 1][ad0]) = a0;
            *(f16x8*)(&As[cur ^ 1][ad1]) = a1;
            *(f16x8*)(&Bs[cur ^ 1][ad0]) = b0;
            cur ^= 1;
        }
        __syncthreads();
    }
    #pragma unroll
    for (int mi = 0; mi < 4; ++mi)
        #pragma unroll
        for (int ni = 0; ni < 2; ++ni)
            #pragma unroll
            for (int j = 0; j < 4; ++j)
                C[(size_t)(by*128 + wm*64 + mi*16 + 4*g + j) * 1024
                  + bx*64 + wn*32 + ni*16 + r] = acc[mi][ni][j];
}

// ---------------- launch ----------------

extern "C" void kernel_launch(void* const* d_in, const int* in_sizes, int n_in,
                              void* d_out, int out_size, void* d_ws, size_t ws_size,
                              hipStream_t stream) {
    const float* q = (const float*)d_in[0];
    const float* k = (const float*)d_in[1];
    const float* v = (const float*)d_in[2];
    const float* w = (const float*)d_in[3];
    float* out = (float*)d_out;

    char* ws = (char*)d_ws;                       // needs 15 MiB
    float2*   tb = (float2*)(ws);
    _Float16* Kr = (_Float16*)(ws + ((size_t)1 << 20));
    _Float16* Vt = (_Float16*)(ws + ((size_t)3 << 20));
    _Float16* Wt = (_Float16*)(ws + ((size_t)5 << 20));
    _Float16* AO = (_Float16*)(ws + ((size_t)7 << 20));

    hipLaunchKernelGGL(prep_kernel,  dim3(2816), dim3(256), 0, stream, k, v, w, tb, Kr, Vt, Wt);
    hipLaunchKernelGGL(attn_kernel,  dim3(512),  dim3(256), 0, stream, q, tb, Kr, Vt, AO);
    hipLaunchKernelGGL(gemm_kernel,  dim3(512),  dim3(256), 0, stream, AO, Wt, out);
}